// Round 2
// baseline (598.089 us; speedup 1.0000x reference)
//
#include <hip/hip_runtime.h>

#define B_ 16
#define N_ 2048
#define M_ 2048
#define ROWS 32    // rows per block (band)
#define WROWS 8    // rows per wave (4 waves/block)
#define GRP 8      // batches per group (L3 working set ~140 MB < 256 MB)

__device__ __forceinline__ float wave_sum(float v) {
#pragma unroll
    for (int off = 32; off >= 1; off >>= 1) v += __shfl_xor(v, off);
    return v;
}

// Pass 1: row_gt/row_cnt (row sums of pred*gt, gt) + col_gt/col_cnt (col sums)
extern "C" __global__ __launch_bounds__(256) void k_pass1(
    const float* __restrict__ pred, const float* __restrict__ gt,
    const int* __restrict__ src_ns, const int* __restrict__ tgt_ns,
    float* __restrict__ row_gt, float* __restrict__ row_cnt,
    float* __restrict__ col_gt, float* __restrict__ col_cnt, int b0)
{
    const int b = b0 + blockIdx.y;
    const int src = src_ns[b];
    const int band = blockIdx.x;
    if (band * ROWS >= src) return;   // whole band masked out
    const int tgt = tgt_ns[b];
    const int wave = threadIdx.x >> 6, lane = threadIdx.x & 63;
    const int base = b * (N_ * M_);

    float4 acg[8], accn[8];
#pragma unroll
    for (int j = 0; j < 8; ++j) { acg[j] = make_float4(0,0,0,0); accn[j] = make_float4(0,0,0,0); }

    const int row0 = band * ROWS + wave * WROWS;
    for (int r = 0; r < WROWS; ++r) {
        const int n = row0 + r;
        if (n >= src) break;          // rows ascending; wave-uniform
        const float4* prow = (const float4*)(pred + base + n * M_);
        const float4* grow = (const float4*)(gt + base + n * M_);
        float rg = 0.f, rc = 0.f;
#pragma unroll
        for (int j = 0; j < 8; ++j) {
            if (j * 256 >= tgt) break;     // wave-uniform dead-chunk skip
            const int m4 = j * 64 + lane;
            const float4 p4 = prow[m4];
            const float4 g4 = grow[m4];
            const int mb = m4 * 4;
#define P1C(K, MB) do { \
    const bool ok = (mb + K) < tgt; \
    float p = fminf(fmaxf(p4.MB, 0.f), 1.f); p = ok ? p : 0.f; \
    const float g = ok ? g4.MB : 0.f; \
    const float gp = p * g; \
    rg += gp; rc += g; \
    acg[j].MB += gp; accn[j].MB += g; \
} while (0)
            P1C(0, x); P1C(1, y); P1C(2, z); P1C(3, w);
#undef P1C
        }
        rg = wave_sum(rg); rc = wave_sum(rc);
        if (lane == 0) { row_gt[b * N_ + n] = rg; row_cnt[b * N_ + n] = rc; }
    }

    // combine column partials across the 4 waves in LDS (sequential rounds, no atomics)
    __shared__ float4 s_cg[M_ / 4];
    __shared__ float4 s_cc[M_ / 4];
    for (int i = threadIdx.x; i < M_ / 4; i += 256) {
        s_cg[i] = make_float4(0,0,0,0);
        s_cc[i] = make_float4(0,0,0,0);
    }
    __syncthreads();
    for (int w = 0; w < 4; ++w) {
        if (wave == w) {
#pragma unroll
            for (int j = 0; j < 8; ++j) {
                const int i = j * 64 + lane;
                float4 v = s_cg[i];
                v.x += acg[j].x; v.y += acg[j].y; v.z += acg[j].z; v.w += acg[j].w;
                s_cg[i] = v;
                float4 u = s_cc[i];
                u.x += accn[j].x; u.y += accn[j].y; u.z += accn[j].z; u.w += accn[j].w;
                s_cc[i] = u;
            }
        }
        __syncthreads();
    }
    const float* fcg = (const float*)s_cg;
    const float* fcc = (const float*)s_cc;
    for (int i = threadIdx.x; i < M_; i += 256) {
        const float v = fcg[i];
        const float u = fcc[i];
        if (v != 0.f) atomicAdd(&col_gt[b * M_ + i], v);   // adding 0 is a no-op: skip
        if (u != 0.f) atomicAdd(&col_cnt[b * M_ + i], u);
    }
}

// Pass 2: src_neg/src_pos (row reductions) + tgt_neg (col reduction)
extern "C" __global__ __launch_bounds__(256) void k_pass2(
    const float* __restrict__ pred, const float* __restrict__ gt,
    const int* __restrict__ src_ns, const int* __restrict__ tgt_ns,
    const float* __restrict__ beta_p,
    const float* __restrict__ row_gt, const float* __restrict__ row_cnt,
    const float* __restrict__ col_gt, const float* __restrict__ col_cnt,
    float* __restrict__ src_neg, float* __restrict__ src_pos,
    float* __restrict__ tgt_neg, int b0)
{
    const int b = b0 + blockIdx.y;
    const int src = src_ns[b];
    const int band = blockIdx.x;
    if (band * ROWS >= src) return;
    const int tgt = tgt_ns[b];
    const float beta = beta_p[0];
    const int wave = threadIdx.x >> 6, lane = threadIdx.x & 63;
    const int base = b * (N_ * M_);

    float4 cg[8], cc[8], tn[8];
    const float4* cg4 = (const float4*)(col_gt + b * M_);
    const float4* cc4 = (const float4*)(col_cnt + b * M_);
#pragma unroll
    for (int j = 0; j < 8; ++j) {
        tn[j] = make_float4(0,0,0,0);
        if (j * 256 < tgt) {
            cg[j] = cg4[j * 64 + lane];
            cc[j] = cc4[j * 64 + lane];
        } else {
            cg[j] = make_float4(0,0,0,0);
            cc[j] = make_float4(0,0,0,0);
        }
    }

    const int row0 = band * ROWS + wave * WROWS;
    for (int r = 0; r < WROWS; ++r) {
        const int n = row0 + r;
        if (n >= src) break;
        const float rg = row_gt[b * N_ + n];
        const float rc = row_cnt[b * N_ + n];
        const float rth = rg - beta;
        const float4* prow = (const float4*)(pred + base + n * M_);
        const float4* grow = (const float4*)(gt + base + n * M_);
        float sneg = 0.f, spos = 0.f;
#pragma unroll
        for (int j = 0; j < 8; ++j) {
            if (j * 256 >= tgt) break;     // wave-uniform dead-chunk skip
            const int m4 = j * 64 + lane;
            const float4 p4 = prow[m4];
            const float4 g4 = grow[m4];
            const int mb = m4 * 4;
#define P2C(K, MB) do { \
    const bool ok = (mb + K) < tgt; \
    float p = fminf(fmaxf(p4.MB, 0.f), 1.f); p = ok ? p : 0.f; \
    const float g = ok ? g4.MB : 0.f; \
    const float gp = p * g; \
    const float as = (ok && (p >= rth)) ? rc : 0.f; \
    const float ds = (as - g) * p; \
    sneg += ds * ds; spos += gp * gp; \
    const float at = (ok && (p >= cg[j].MB - beta)) ? cc[j].MB : 0.f; \
    const float dt = (at - g) * p; \
    tn[j].MB += dt * dt; \
} while (0)
            P2C(0, x); P2C(1, y); P2C(2, z); P2C(3, w);
#undef P2C
        }
        sneg = wave_sum(sneg); spos = wave_sum(spos);
        if (lane == 0) { src_neg[b * N_ + n] = sneg; src_pos[b * N_ + n] = spos; }
    }

    __shared__ float4 s_tn[M_ / 4];
    for (int i = threadIdx.x; i < M_ / 4; i += 256) s_tn[i] = make_float4(0,0,0,0);
    __syncthreads();
    for (int w = 0; w < 4; ++w) {
        if (wave == w) {
#pragma unroll
            for (int j = 0; j < 8; ++j) {
                const int i = j * 64 + lane;
                float4 v = s_tn[i];
                v.x += tn[j].x; v.y += tn[j].y; v.z += tn[j].z; v.w += tn[j].w;
                s_tn[i] = v;
            }
        }
        __syncthreads();
    }
    const float* ftn = (const float*)s_tn;
    for (int i = threadIdx.x; i < M_; i += 256) {
        const float v = ftn[i];
        if (v != 0.f) atomicAdd(&tgt_neg[b * M_ + i], v);
    }
}

// Final: corr[b] = dot(tgt_neg, col_cnt), then loss reduction -> single scalar
extern "C" __global__ __launch_bounds__(256) void k_final(
    const float* __restrict__ src_neg, const float* __restrict__ src_pos,
    const float* __restrict__ tgt_neg, const float* __restrict__ col_cnt,
    const int* __restrict__ src_ns, float* __restrict__ out)
{
    const int b = blockIdx.x;
    const int wave = threadIdx.x >> 6, lane = threadIdx.x & 63;
    __shared__ float sredc[4];
    __shared__ float sredl[4];

    float c = 0.f;
    for (int i = threadIdx.x; i < M_; i += 256)
        c += tgt_neg[b * M_ + i] * col_cnt[b * M_ + i];
    c = wave_sum(c);
    if (lane == 0) sredc[wave] = c;
    __syncthreads();
    const float corr = sredc[0] + sredc[1] + sredc[2] + sredc[3];

    const int src = src_ns[b];
    float ls = 0.f;
    for (int n = threadIdx.x; n < src; n += 256) {
        const float sp = src_pos[b * N_ + n];
        const float sn = src_neg[b * N_ + n];
        ls += logf(sp) - logf(1.f + sn + corr);
    }
    ls = wave_sum(ls);
    if (lane == 0) sredl[wave] = ls;
    __syncthreads();
    if (threadIdx.x == 0) {
        const float total = sredl[0] + sredl[1] + sredl[2] + sredl[3];
        float nsum = 0.f;
        for (int i = 0; i < B_; ++i) nsum += (float)src_ns[i];
        atomicAdd(out, -0.5f * total / nsum);
    }
}

extern "C" void kernel_launch(void* const* d_in, const int* in_sizes, int n_in,
                              void* d_out, int out_size, void* d_ws, size_t ws_size,
                              hipStream_t stream)
{
    const float* pred   = (const float*)d_in[0];
    const float* gtp    = (const float*)d_in[1];
    const int*   src_ns = (const int*)d_in[2];
    const int*   tgt_ns = (const int*)d_in[3];
    const float* beta   = (const float*)d_in[4];
    float* out = (float*)d_out;
    float* ws  = (float*)d_ws;

    // atomic-accumulated arrays first (single contiguous memset)
    float* col_gt  = ws;
    float* col_cnt = col_gt  + B_ * M_;
    float* tgt_neg = col_cnt + B_ * M_;
    float* row_gt  = tgt_neg + B_ * M_;
    float* row_cnt = row_gt  + B_ * N_;
    float* src_neg = row_cnt + B_ * N_;
    float* src_pos = src_neg + B_ * N_;

    const size_t zero_bytes = (size_t)(3 * B_ * M_) * sizeof(float);
    hipMemsetAsync(d_ws, 0, zero_bytes, stream);
    hipMemsetAsync(d_out, 0, sizeof(float), stream);

    // grouped passes: P2(g) re-reads pred/gt while the group (~140 MB valid)
    // is still resident in the 256 MB Infinity Cache
    dim3 grid(N_ / ROWS, GRP);
    for (int g = 0; g < B_ / GRP; ++g) {
        const int b0 = g * GRP;
        k_pass1<<<grid, 256, 0, stream>>>(pred, gtp, src_ns, tgt_ns,
                                          row_gt, row_cnt, col_gt, col_cnt, b0);
        k_pass2<<<grid, 256, 0, stream>>>(pred, gtp, src_ns, tgt_ns, beta,
                                          row_gt, row_cnt, col_gt, col_cnt,
                                          src_neg, src_pos, tgt_neg, b0);
    }
    k_final<<<B_, 256, 0, stream>>>(src_neg, src_pos, tgt_neg, col_cnt, src_ns, out);
}

// Round 3
// 566.895 us; speedup vs baseline: 1.0550x; 1.0550x over previous
//
#include <hip/hip_runtime.h>

#define B_ 16
#define N_ 2048
#define M_ 2048
#define ROWS 32    // rows per block (band)
#define WROWS 8    // rows per wave (4 waves/block)
#define BN (B_ * N_)
#define BM (B_ * M_)

__device__ __forceinline__ float wave_sum(float v) {
#pragma unroll
    for (int off = 32; off >= 1; off >>= 1) v += __shfl_xor(v, off);
    return v;
}

// K1: stream gt ONCE. Find nonzeros, gather the matching pred value, build
// row/col stats (row_gt,row_cnt,col_gt,col_cnt) and sparse records.
extern "C" __global__ __launch_bounds__(256) void k_scan_gt(
    const float* __restrict__ gt, const float* __restrict__ pred,
    const int* __restrict__ src_ns, const int* __restrict__ tgt_ns,
    float* __restrict__ row_gt, float* __restrict__ row_cnt,
    float* __restrict__ col_gt, float* __restrict__ col_cnt,
    int* __restrict__ sp_cnt, int* __restrict__ sp_m,
    float* __restrict__ sp_g, float* __restrict__ sp_p)
{
    const int b = blockIdx.y;
    const int src = src_ns[b];
    if (blockIdx.x * ROWS >= src) return;
    const int tgt = tgt_ns[b];
    const int wave = threadIdx.x >> 6, lane = threadIdx.x & 63;
    const int base = b * (N_ * M_);
    const int row0 = blockIdx.x * ROWS + wave * WROWS;

    for (int r = 0; r < WROWS; ++r) {
        const int n = row0 + r;
        if (n >= src) break;                 // wave-uniform
        const float4* grow = (const float4*)(gt + base + n * M_);
#pragma unroll
        for (int j = 0; j < 8; ++j) {
            if (j * 256 >= tgt) break;       // wave-uniform dead-chunk skip
            const int m4 = j * 64 + lane;
            const float4 g4 = grow[m4];
            const int mb = m4 * 4;
#define SCAN(K, MB) do { \
    const int m = mb + K; \
    const float gv = g4.MB; \
    if (m < tgt && gv != 0.f) { \
        float pv = pred[base + n * M_ + m]; \
        pv = fminf(fmaxf(pv, 0.f), 1.f); \
        const int bn = b * N_ + n; \
        const float gp = pv * gv; \
        atomicAdd(&row_gt[bn], gp); \
        atomicAdd(&row_cnt[bn], gv); \
        atomicAdd(&col_gt[b * M_ + m], gp); \
        atomicAdd(&col_cnt[b * M_ + m], gv); \
        const int slot = atomicAdd(&sp_cnt[bn], 1); \
        if (slot < 2) { \
            sp_m[slot * BN + bn] = m; \
            sp_g[slot * BN + bn] = gv; \
            sp_p[slot * BN + bn] = pv; \
        } \
    } \
} while (0)
            SCAN(0, x); SCAN(1, y); SCAN(2, z); SCAN(3, w);
#undef SCAN
        }
    }
}

// K2: stream pred ONCE. Dense parts: src_neg_dense[n] = sum_m rc^2*ind*p^2,
// tgt_neg_dense[m] = sum_n cc^2*ind*p^2.
extern "C" __global__ __launch_bounds__(256) void k_stream_pred(
    const float* __restrict__ pred,
    const int* __restrict__ src_ns, const int* __restrict__ tgt_ns,
    const float* __restrict__ beta_p,
    const float* __restrict__ row_gt, const float* __restrict__ row_cnt,
    const float* __restrict__ col_gt, const float* __restrict__ col_cnt,
    float* __restrict__ src_neg, float* __restrict__ tgt_neg)
{
    const int b = blockIdx.y;
    const int src = src_ns[b];
    if (blockIdx.x * ROWS >= src) return;
    const int tgt = tgt_ns[b];
    const float beta = beta_p[0];
    const int wave = threadIdx.x >> 6, lane = threadIdx.x & 63;
    const int base = b * (N_ * M_);

    float4 cgb[8], cc2[8], tn[8];            // cg - beta, cc^2, col accumulator
    const float4* cg4 = (const float4*)(col_gt + b * M_);
    const float4* cc4 = (const float4*)(col_cnt + b * M_);
#pragma unroll
    for (int j = 0; j < 8; ++j) {
        tn[j] = make_float4(0, 0, 0, 0);
        if (j * 256 < tgt) {
            const float4 cg = cg4[j * 64 + lane];
            const float4 cv = cc4[j * 64 + lane];
            cgb[j] = make_float4(cg.x - beta, cg.y - beta, cg.z - beta, cg.w - beta);
            cc2[j] = make_float4(cv.x * cv.x, cv.y * cv.y, cv.z * cv.z, cv.w * cv.w);
        } else {
            cgb[j] = make_float4(0, 0, 0, 0);
            cc2[j] = make_float4(0, 0, 0, 0);
        }
    }

    const int row0 = blockIdx.x * ROWS + wave * WROWS;
    for (int r = 0; r < WROWS; ++r) {
        const int n = row0 + r;
        if (n >= src) break;
        const int bn = b * N_ + n;
        const float rg = row_gt[bn];
        const float rc = row_cnt[bn];
        const float rth = rg - beta;
        const float rc2 = rc * rc;
        const float4* prow = (const float4*)(pred + base + n * M_);
        float sneg = 0.f;
#pragma unroll
        for (int j = 0; j < 8; ++j) {
            if (j * 256 >= tgt) break;
            const int m4 = j * 64 + lane;
            const float4 p4 = prow[m4];
            const int mb = m4 * 4;
#define DENSE(K, MB) do { \
    const bool ok = (mb + K) < tgt; \
    float p = fminf(fmaxf(p4.MB, 0.f), 1.f); p = ok ? p : 0.f; \
    const float ps = p * p; \
    sneg += (p >= rth) ? rc2 * ps : 0.f; \
    tn[j].MB += (p >= cgb[j].MB) ? cc2[j].MB * ps : 0.f; \
} while (0)
            DENSE(0, x); DENSE(1, y); DENSE(2, z); DENSE(3, w);
#undef DENSE
        }
        sneg = wave_sum(sneg);
        if (lane == 0) src_neg[bn] = sneg;
    }

    // combine column partials across the 4 waves in LDS, then global atomics
    __shared__ float4 s_tn[M_ / 4];
    for (int i = threadIdx.x; i < M_ / 4; i += 256) s_tn[i] = make_float4(0, 0, 0, 0);
    __syncthreads();
    for (int w = 0; w < 4; ++w) {
        if (wave == w) {
#pragma unroll
            for (int j = 0; j < 8; ++j) {
                const int i = j * 64 + lane;
                float4 v = s_tn[i];
                v.x += tn[j].x; v.y += tn[j].y; v.z += tn[j].z; v.w += tn[j].w;
                s_tn[i] = v;
            }
        }
        __syncthreads();
    }
    const float* ftn = (const float*)s_tn;
    for (int i = threadIdx.x; i < M_; i += 256) {
        const float v = ftn[i];
        if (v != 0.f) atomicAdd(&tgt_neg[b * M_ + i], v);   // adding 0 is a no-op
    }
}

// K3: one block per batch. Phase A: sparse g-corrections (all touch only this
// batch's arrays). Phase B: corr = dot(tgt_neg, col_cnt). Phase C: loss.
extern "C" __global__ __launch_bounds__(256) void k_final(
    const int* __restrict__ src_ns, const float* __restrict__ beta_p,
    const float* __restrict__ row_gt, const float* __restrict__ row_cnt,
    const float* __restrict__ col_gt, const float* __restrict__ col_cnt,
    const int* __restrict__ sp_cnt, const int* __restrict__ sp_m,
    const float* __restrict__ sp_g, const float* __restrict__ sp_p,
    float* __restrict__ src_neg, float* __restrict__ src_pos,
    float* __restrict__ tgt_neg, float* __restrict__ out)
{
    const int b = blockIdx.x;
    const float beta = beta_p[0];
    const int wave = threadIdx.x >> 6, lane = threadIdx.x & 63;
    __shared__ float sredc[4];
    __shared__ float sredl[4];

    // Phase A: corrections  (g^2 - 2*att*g) * p^2  at each gt-nonzero
    for (int n = threadIdx.x; n < N_; n += 256) {
        const int bn = b * N_ + n;
        int cnt = sp_cnt[bn];
        if (cnt <= 0) continue;
        if (cnt > 2) cnt = 2;
        const float rg = row_gt[bn];
        const float rc = row_cnt[bn];
        float add_pos = 0.f, add_neg = 0.f;
        for (int s = 0; s < cnt; ++s) {
            const int m = sp_m[s * BN + bn];
            const float gv = sp_g[s * BN + bn];
            const float pv = sp_p[s * BN + bn];
            const float pv2 = pv * pv;
            add_pos += (pv * gv) * (pv * gv);
            const float as = (pv >= rg - beta) ? rc : 0.f;
            add_neg += (gv * gv - 2.f * as * gv) * pv2;
            const float ccm = col_cnt[b * M_ + m];
            const float at = (pv >= col_gt[b * M_ + m] - beta) ? ccm : 0.f;
            atomicAdd(&tgt_neg[b * M_ + m], (gv * gv - 2.f * at * gv) * pv2);
        }
        src_pos[bn] += add_pos;   // single writer per row
        src_neg[bn] += add_neg;   // single writer per row (K2 wrote dense part)
    }
    __threadfence();
    __syncthreads();

    // Phase B: corr
    float c = 0.f;
    for (int i = threadIdx.x; i < M_; i += 256)
        c += tgt_neg[b * M_ + i] * col_cnt[b * M_ + i];
    c = wave_sum(c);
    if (lane == 0) sredc[wave] = c;
    __syncthreads();
    const float corr = sredc[0] + sredc[1] + sredc[2] + sredc[3];

    // Phase C: loss
    const int src = src_ns[b];
    float ls = 0.f;
    for (int n = threadIdx.x; n < src; n += 256) {
        const float sp = src_pos[b * N_ + n];
        const float sn = src_neg[b * N_ + n];
        ls += logf(sp) - logf(1.f + sn + corr);
    }
    ls = wave_sum(ls);
    if (lane == 0) sredl[wave] = ls;
    __syncthreads();
    if (threadIdx.x == 0) {
        const float total = sredl[0] + sredl[1] + sredl[2] + sredl[3];
        float nsum = 0.f;
        for (int i = 0; i < B_; ++i) nsum += (float)src_ns[i];
        atomicAdd(out, -0.5f * total / nsum);
    }
}

extern "C" void kernel_launch(void* const* d_in, const int* in_sizes, int n_in,
                              void* d_out, int out_size, void* d_ws, size_t ws_size,
                              hipStream_t stream)
{
    const float* pred   = (const float*)d_in[0];
    const float* gtp    = (const float*)d_in[1];
    const int*   src_ns = (const int*)d_in[2];
    const int*   tgt_ns = (const int*)d_in[3];
    const float* beta   = (const float*)d_in[4];
    float* out = (float*)d_out;
    float* ws  = (float*)d_ws;

    // zero-initialized region (single contiguous memset)
    float* col_gt  = ws;                     // BM
    float* col_cnt = col_gt  + BM;           // BM
    float* tgt_neg = col_cnt + BM;           // BM
    float* row_gt  = tgt_neg + BM;           // BN
    float* row_cnt = row_gt  + BN;           // BN
    float* src_pos = row_cnt + BN;           // BN
    int*   sp_cnt  = (int*)(src_pos + BN);   // BN
    // non-zeroed region
    float* src_neg = (float*)(sp_cnt + BN);  // BN (densely written by K2)
    int*   sp_m    = (int*)(src_neg + BN);   // 2*BN
    float* sp_g    = (float*)(sp_m + 2 * BN);// 2*BN
    float* sp_p    = sp_g + 2 * BN;          // 2*BN

    const size_t zero_bytes = (size_t)(3 * BM + 4 * BN) * sizeof(float);
    hipMemsetAsync(d_ws, 0, zero_bytes, stream);
    hipMemsetAsync(d_out, 0, sizeof(float), stream);

    dim3 grid(N_ / ROWS, B_);
    k_scan_gt<<<grid, 256, 0, stream>>>(gtp, pred, src_ns, tgt_ns,
                                        row_gt, row_cnt, col_gt, col_cnt,
                                        sp_cnt, sp_m, sp_g, sp_p);
    k_stream_pred<<<grid, 256, 0, stream>>>(pred, src_ns, tgt_ns, beta,
                                            row_gt, row_cnt, col_gt, col_cnt,
                                            src_neg, tgt_neg);
    k_final<<<B_, 256, 0, stream>>>(src_ns, beta, row_gt, row_cnt,
                                    col_gt, col_cnt, sp_cnt, sp_m, sp_g, sp_p,
                                    src_neg, src_pos, tgt_neg, out);
}